// Round 5
// baseline (1898.031 us; speedup 1.0000x reference)
//
#include <hip/hip_runtime.h>
#include <math.h>

#define NNODES 100000
#define NEDGES 3200000
#define NFEAT  500
#define HID    64
#define NCLS   40
#define NLAYERS 8
#define NPB    8                 // spmm nodes per block
#define NODES_PER_PART 12500     // NNODES / 8 (XCD-partitioned build)
#define NBP    1594              // phase-B blocks per part
#define PART_CAP (NBP * 256)     // 408064 staged-edge capacity per part (E/8=400k)

typedef __attribute__((ext_vector_type(8))) short short8;   // 8 bf16 (4 VGPRs)
typedef __attribute__((ext_vector_type(4))) float floatx4;  // MFMA acc

static __device__ __forceinline__ float b2f(unsigned short u) {
    return __uint_as_float(((unsigned)u) << 16);
}
static __device__ __forceinline__ unsigned short f2b(float f) {
    unsigned u = __float_as_uint(f);
    return (unsigned short)((u + 0x7FFFu + ((u >> 16) & 1u)) >> 16);  // RNE
}
static __device__ __forceinline__ ushort4 pk4(float4 v) {
    return make_ushort4(f2b(v.x), f2b(v.y), f2b(v.z), f2b(v.w));
}

// ---------------- lin0: h0 = relu(x @ W + b)  --  MFMA bf16 GEMM ----------------
__global__ __launch_bounds__(256) void lin0_kernel(const float* __restrict__ x,
    const float* __restrict__ w, const float* __restrict__ b,
    unsigned short* __restrict__ h0)
{
    __shared__ unsigned short as_[128][40];  // A tile bf16 [m][k], rows padded 32->40
    __shared__ unsigned short wt[64][40];    // W^T chunk bf16 [n][k]
    const int tid = threadIdx.x;
    const int wv = tid >> 6, lane = tid & 63;
    const int ln15 = lane & 15, q = lane >> 4;
    const int m0 = blockIdx.x * 128;

    floatx4 acc[2][4];
#pragma unroll
    for (int i = 0; i < 2; ++i)
#pragma unroll
        for (int t = 0; t < 4; ++t) acc[i][t] = (floatx4){0.f, 0.f, 0.f, 0.f};

    const int r_ = tid >> 1, hh = tid & 1;
    int gms = m0 + r_; if (gms >= NNODES) gms = NNODES - 1;
    const float* xrow = x + (size_t)gms * NFEAT;

    for (int c = 0; c < 16; ++c) {
        const int k0 = c * 32;
        {
            float4 v0, v1, v2, v3;
            if (c < 15 || hh == 0) {
                const float4* p4 = (const float4*)(xrow + k0 + 16 * hh);
                v0 = p4[0]; v1 = p4[1]; v2 = p4[2]; v3 = p4[3];
            } else {
                v0 = *(const float4*)(xrow + 496);
                v1 = make_float4(0, 0, 0, 0); v2 = v1; v3 = v1;
            }
            ushort4* dst4 = (ushort4*)&as_[r_][16 * hh];
            dst4[0] = pk4(v0); dst4[1] = pk4(v1); dst4[2] = pk4(v2); dst4[3] = pk4(v3);
        }
#pragma unroll
        for (int ii = 0; ii < 2; ++ii) {
            int i = tid + ii * 256;
            int k = i >> 4, nb = (i & 15) * 4;
            float4 v = make_float4(0, 0, 0, 0);
            if (c < 15 || i < 320)
                v = ((const float4*)(w + (size_t)k0 * HID))[i];
            wt[nb + 0][k] = f2b(v.x); wt[nb + 1][k] = f2b(v.y);
            wt[nb + 2][k] = f2b(v.z); wt[nb + 3][k] = f2b(v.w);
        }
        __syncthreads();
        short8 af[2], bfr[4];
#pragma unroll
        for (int mt = 0; mt < 2; ++mt)
            af[mt] = *(const short8*)&as_[32 * wv + 16 * mt + ln15][8 * q];
#pragma unroll
        for (int t = 0; t < 4; ++t)
            bfr[t] = *(const short8*)&wt[16 * t + ln15][8 * q];
#pragma unroll
        for (int mt = 0; mt < 2; ++mt)
#pragma unroll
            for (int t = 0; t < 4; ++t)
                acc[mt][t] = __builtin_amdgcn_mfma_f32_16x16x32_bf16(
                    af[mt], bfr[t], acc[mt][t], 0, 0, 0);
        __syncthreads();
    }
    float bv[4];
#pragma unroll
    for (int t = 0; t < 4; ++t) bv[t] = b[16 * t + ln15];
#pragma unroll
    for (int mt = 0; mt < 2; ++mt)
#pragma unroll
        for (int r = 0; r < 4; ++r) {
            int gm = m0 + 32 * wv + 16 * mt + q * 4 + r;
            if (gm < NNODES) {
#pragma unroll
                for (int t = 0; t < 4; ++t)
                    h0[(size_t)gm * HID + 16 * t + ln15] =
                        f2b(fmaxf(acc[mt][t][r] + bv[t], 0.f));
            }
        }
}

// ---------------- CSR build, two-phase binned ----------------
// Phase A: one pass over edges; wave-ballot compaction into 8 per-part staging
// buffers of packed records d(17)|s(17)|w_bf16(16).
__global__ __launch_bounds__(256) void bin_kernel(const int* __restrict__ src,
    const int* __restrict__ dst, const float* __restrict__ w,
    unsigned long long* __restrict__ staged, int* __restrict__ pcount)
{
    const int e = blockIdx.x * 256 + threadIdx.x;   // grid covers E exactly
    const int d = dst[e];
    const int s = src[e];
    const float wt = w[e];
    const int part = d / NODES_PER_PART;
    unsigned long long m[8];
#pragma unroll
    for (int p = 0; p < 8; ++p) m[p] = __ballot(part == p);
    const int lane = threadIdx.x & 63;
    const unsigned long long below = (1ull << lane) - 1ull;   // lanes < lane
    int basep = 0;
    if (lane < 8) basep = atomicAdd(&pcount[lane], __popcll(m[lane]));
    const int mybase = __shfl(basep, part, 64);
    const int slot = mybase + __popcll(m[part] & below);
    const unsigned long long pk = (unsigned long long)(unsigned)d |
        ((unsigned long long)(unsigned)s << 17) |
        ((unsigned long long)f2b(wt) << 34);
    staged[(size_t)part * PART_CAP + slot] = pk;
}

// Phase B1: degree count from staged (XCD-local atomics, nt reads).
__global__ __launch_bounds__(256) void count2_kernel(
    const unsigned long long* __restrict__ staged, const int* __restrict__ pcount,
    int* __restrict__ deg)
{
    const int part = blockIdx.x & 7;
    const int idx = (blockIdx.x >> 3) * 256 + threadIdx.x;
    if (idx < pcount[part]) {
        unsigned long long pk =
            __builtin_nontemporal_load(&staged[(size_t)part * PART_CAP + idx]);
        atomicAdd(&deg[(int)(pk & 0x1FFFFu)], 1);
    }
}

__global__ __launch_bounds__(1024) void chunk_sum_kernel(const int* __restrict__ deg,
                                                         int* __restrict__ csum)
{
    __shared__ int s[1024];
    int i = blockIdx.x * 1024 + threadIdx.x;
    s[threadIdx.x] = (i < NNODES) ? ((deg[i] + 3) & ~3) : 0;
    __syncthreads();
    for (int off = 512; off > 0; off >>= 1) {
        if (threadIdx.x < off) s[threadIdx.x] += s[threadIdx.x + off];
        __syncthreads();
    }
    if (threadIdx.x == 0) csum[blockIdx.x] = s[0];
}

__global__ void chunk_base_kernel(const int* __restrict__ csum, int* __restrict__ cbase,
                                  int* __restrict__ offs, int nchunks)
{
    int run = 0;
    for (int i = 0; i < nchunks; ++i) { cbase[i] = run; run += csum[i]; }
    offs[NNODES] = run;
}

__global__ __launch_bounds__(1024) void scan_kernel(const int* __restrict__ deg,
    const int* __restrict__ cbase, int* __restrict__ offs, int* __restrict__ cursor)
{
    __shared__ int s[1024];
    int i = blockIdx.x * 1024 + threadIdx.x;
    int v = (i < NNODES) ? ((deg[i] + 3) & ~3) : 0;
    s[threadIdx.x] = v;
    __syncthreads();
    for (int off = 1; off < 1024; off <<= 1) {
        int t = (threadIdx.x >= off) ? s[threadIdx.x - off] : 0;
        __syncthreads();
        s[threadIdx.x] += t;
        __syncthreads();
    }
    if (i < NNODES) {
        int excl = cbase[blockIdx.x] + s[threadIdx.x] - v;
        offs[i] = excl;
        cursor[i] = excl;
    }
}

// Phase B2: scatter from staged into CSR (XCD-local region, nt reads so the
// stream doesn't evict partially-written CSR lines from L2).
__global__ __launch_bounds__(256) void scatter2_kernel(
    const unsigned long long* __restrict__ staged, const int* __restrict__ pcount,
    int* __restrict__ cursor, int2* __restrict__ srcw)
{
    const int part = blockIdx.x & 7;
    const int idx = (blockIdx.x >> 3) * 256 + threadIdx.x;
    if (idx < pcount[part]) {
        unsigned long long pk =
            __builtin_nontemporal_load(&staged[(size_t)part * PART_CAP + idx]);
        const int d = (int)(pk & 0x1FFFFu);
        const int s = (int)((pk >> 17) & 0x1FFFFu);
        const float wf = b2f((unsigned short)(pk >> 34));
        int pos = atomicAdd(&cursor[d], 1);
        srcw[pos] = make_int2(s * 128, __float_as_int(wf));  // byte offset, fp32 w
    }
}

__global__ __launch_bounds__(256) void pad_kernel(const int* __restrict__ offs,
    const int* __restrict__ deg, int2* __restrict__ srcw)
{
    int n = blockIdx.x * 256 + threadIdx.x;
    if (n < NNODES) {
        int e = offs[n] + deg[n], e1 = offs[n + 1];
        for (; e < e1; ++e) srcw[e] = make_int2(0, 0);
    }
}

// ---------------- fused SpMM + blend + dense + relu layer ----------------
__global__ __launch_bounds__(256) void spmm_layer_kernel(
    const unsigned short* __restrict__ h_in, const unsigned short* __restrict__ x0,
    unsigned short* __restrict__ h_out, const int* __restrict__ offs,
    const int2* __restrict__ srcw, const float* __restrict__ Wg, float beta)
{
    __shared__ float WlT[HID][68];   // WlT[j][k] = Wg[k][j], 68-pad: conflict-free b128
    __shared__ float zs[NPB][HID];
    for (int i = threadIdx.x; i < 1024; i += 256) {
        float4 v = ((const float4*)Wg)[i];
        int k = i >> 4, j = (i & 15) * 4;
        WlT[j + 0][k] = v.x; WlT[j + 1][k] = v.y;
        WlT[j + 2][k] = v.z; WlT[j + 3][k] = v.w;
    }
    const int wv = threadIdx.x >> 6, lane = threadIdx.x & 63;
    const int half = lane >> 5, ln = lane & 31;
    const int nloc = wv + half * 4;
    const int n = blockIdx.x * NPB + nloc;
    int e = offs[n];
    const int e1 = offs[n + 1];
    const char* hb = (const char*)h_in;
    float a0 = 0.f, a1 = 0.f;
    for (; e < e1; e += 4) {         // deg padded to multiple of 4, 4 gathers in flight
        int4 p = *(const int4*)(srcw + e);
        int4 q = *(const int4*)(srcw + e + 2);
        unsigned v0 = *(const unsigned*)(hb + p.x + ln * 4);
        unsigned v1 = *(const unsigned*)(hb + p.z + ln * 4);
        unsigned v2 = *(const unsigned*)(hb + q.x + ln * 4);
        unsigned v3 = *(const unsigned*)(hb + q.z + ln * 4);
        float w0 = __int_as_float(p.y), w1 = __int_as_float(p.w);
        float w2 = __int_as_float(q.y), w3 = __int_as_float(q.w);
        a0 = fmaf(w0, __uint_as_float(v0 << 16), a0);
        a1 = fmaf(w0, __uint_as_float(v0 & 0xffff0000u), a1);
        a0 = fmaf(w1, __uint_as_float(v1 << 16), a0);
        a1 = fmaf(w1, __uint_as_float(v1 & 0xffff0000u), a1);
        a0 = fmaf(w2, __uint_as_float(v2 << 16), a0);
        a1 = fmaf(w2, __uint_as_float(v2 & 0xffff0000u), a1);
        a0 = fmaf(w3, __uint_as_float(v3 << 16), a0);
        a1 = fmaf(w3, __uint_as_float(v3 & 0xffff0000u), a1);
    }
    unsigned xv = *(const unsigned*)((const char*)x0 + (size_t)n * 128 + ln * 4);
    zs[nloc][2 * ln]     = 0.9f * a0 + 0.1f * __uint_as_float(xv << 16);
    zs[nloc][2 * ln + 1] = 0.9f * a1 + 0.1f * __uint_as_float(xv & 0xffff0000u);
    __syncthreads();
    const int j = lane;
    const int na = 2 * wv, nb = 2 * wv + 1;
    const float4* wrow = (const float4*)WlT[j];
    const float4* zap = (const float4*)zs[na];
    const float4* zbp = (const float4*)zs[nb];
    float mm0 = 0.f, mm1 = 0.f;
#pragma unroll
    for (int k4 = 0; k4 < 16; ++k4) {
        float4 wvv = wrow[k4];
        float4 za = zap[k4], zb = zbp[k4];
        mm0 = fmaf(za.x, wvv.x, mm0); mm1 = fmaf(zb.x, wvv.x, mm1);
        mm0 = fmaf(za.y, wvv.y, mm0); mm1 = fmaf(zb.y, wvv.y, mm1);
        mm0 = fmaf(za.z, wvv.z, mm0); mm1 = fmaf(zb.z, wvv.z, mm1);
        mm0 = fmaf(za.w, wvv.w, mm0); mm1 = fmaf(zb.w, wvv.w, mm1);
    }
    const float ob = 1.f - beta;
    const size_t base = (size_t)blockIdx.x * NPB;
    h_out[(base + na) * HID + j] = f2b(fmaxf(ob * zs[na][j] + beta * mm0, 0.f));
    h_out[(base + nb) * HID + j] = f2b(fmaxf(ob * zs[nb][j] + beta * mm1, 0.f));
}

// ---------------- final: log_softmax(h @ W1 + b1) ----------------
__global__ __launch_bounds__(256) void final_kernel(const unsigned short* __restrict__ h,
    const float* __restrict__ w1, const float* __restrict__ b1, float* __restrict__ out)
{
    const int m = threadIdx.x >> 6, j = threadIdx.x & 63;
    const long n = (long)blockIdx.x * 4 + m;
    const int jj = (j < NCLS) ? j : NCLS - 1;
    const ushort4* hrow = (const ushort4*)(h + n * HID);
    float acc = b1[jj];
#pragma unroll
    for (int k4 = 0; k4 < 16; ++k4) {
        ushort4 hv = hrow[k4];
        const int k = k4 * 4;
        acc = fmaf(b2f(hv.x), w1[(k + 0) * NCLS + jj], acc);
        acc = fmaf(b2f(hv.y), w1[(k + 1) * NCLS + jj], acc);
        acc = fmaf(b2f(hv.z), w1[(k + 2) * NCLS + jj], acc);
        acc = fmaf(b2f(hv.w), w1[(k + 3) * NCLS + jj], acc);
    }
    float lg = (j < NCLS) ? acc : -INFINITY;
    float mx = lg;
#pragma unroll
    for (int o = 32; o > 0; o >>= 1) mx = fmaxf(mx, __shfl_xor(mx, o, 64));
    float ex = (j < NCLS) ? expf(acc - mx) : 0.f;
    float sm = ex;
#pragma unroll
    for (int o = 32; o > 0; o >>= 1) sm += __shfl_xor(sm, o, 64);
    if (j < NCLS) out[n * NCLS + j] = acc - mx - logf(sm);
}

extern "C" void kernel_launch(void* const* d_in, const int* in_sizes, int n_in,
                              void* d_out, int out_size, void* d_ws, size_t ws_size,
                              hipStream_t stream)
{
    const float* x    = (const float*)d_in[0];
    const int*   esrc = (const int*)d_in[1];
    const int*   edst = (const int*)d_in[2];
    const float* ew   = (const float*)d_in[3];
    const float* l0w  = (const float*)d_in[4];
    const float* l0b  = (const float*)d_in[5];
    const float* cw   = (const float*)d_in[6];
    const float* l1w  = (const float*)d_in[7];
    const float* l1b  = (const float*)d_in[8];
    float* out = (float*)d_out;

    char* p = (char*)d_ws;
    unsigned short* h0 = (unsigned short*)p; p += (size_t)NNODES * HID * 2;
    unsigned short* hA = (unsigned short*)p; p += (size_t)NNODES * HID * 2;
    unsigned short* hB = (unsigned short*)p; p += (size_t)NNODES * HID * 2;
    int2*  srcw = (int2*)p;  p += ((size_t)NEDGES + 4 * NNODES) * 8;  // padded CSR
    unsigned long long* staged = (unsigned long long*)p; p += (size_t)8 * PART_CAP * 8;
    int* offs   = (int*)p;   p += (size_t)(NNODES + 1) * 4;
    int* cursor = (int*)p;   p += (size_t)NNODES * 4;
    int* deg    = (int*)p;   p += (size_t)NNODES * 4;
    int* pcount = (int*)p;   p += 64;
    int* csum   = (int*)p;   p += 512;
    int* cbase  = (int*)p;   p += 512;

    const int nchunks = (NNODES + 1023) / 1024;   // 98

    hipMemsetAsync(deg, 0, NNODES * sizeof(int) + 64, stream);  // deg + pcount
    lin0_kernel<<<(NNODES + 127) / 128, 256, 0, stream>>>(x, l0w, l0b, h0);
    bin_kernel<<<NEDGES / 256, 256, 0, stream>>>(esrc, edst, ew, staged, pcount);
    count2_kernel<<<NBP * 8, 256, 0, stream>>>(staged, pcount, deg);
    chunk_sum_kernel<<<nchunks, 1024, 0, stream>>>(deg, csum);
    chunk_base_kernel<<<1, 1, 0, stream>>>(csum, cbase, offs, nchunks);
    scan_kernel<<<nchunks, 1024, 0, stream>>>(deg, cbase, offs, cursor);
    scatter2_kernel<<<NBP * 8, 256, 0, stream>>>(staged, pcount, cursor, srcw);
    pad_kernel<<<(NNODES + 255) / 256, 256, 0, stream>>>(offs, deg, srcw);

    const unsigned short* hin = h0;
    unsigned short* bufs[2] = { hA, hB };
    for (int l = 0; l < NLAYERS; ++l) {
        float beta = (float)log(0.5 / (double)(l + 1) + 1.0);
        unsigned short* hout = bufs[l & 1];
        spmm_layer_kernel<<<NNODES / NPB, 256, 0, stream>>>(
            hin, h0, hout, offs, srcw, cw + (size_t)l * HID * HID, beta);
        hin = hout;
    }
    final_kernel<<<NNODES / 4, 256, 0, stream>>>(hin, l1w, l1b, out);
}

// Round 6
// 1349.379 us; speedup vs baseline: 1.4066x; 1.4066x over previous
//
#include <hip/hip_runtime.h>
#include <math.h>

#define NNODES 100000
#define NEDGES 3200000
#define NFEAT  500
#define HID    64
#define NCLS   40
#define NLAYERS 8
#define NPB    8                 // spmm nodes per block
#define NODES_PER_PART 12500     // NNODES / 8 (XCD-partitioned build)
#define NBP    1594              // phase-B blocks per part
#define PART_CAP (NBP * 256)     // 408064 staged-edge capacity per part (E/8=400k)
#define EPB    2560              // bin: edges per block (10 iters of 256)

typedef __attribute__((ext_vector_type(8))) short short8;   // 8 bf16 (4 VGPRs)
typedef __attribute__((ext_vector_type(4))) float floatx4;  // MFMA acc

static __device__ __forceinline__ float b2f(unsigned short u) {
    return __uint_as_float(((unsigned)u) << 16);
}
static __device__ __forceinline__ unsigned short f2b(float f) {
    unsigned u = __float_as_uint(f);
    return (unsigned short)((u + 0x7FFFu + ((u >> 16) & 1u)) >> 16);  // RNE
}
static __device__ __forceinline__ ushort4 pk4(float4 v) {
    return make_ushort4(f2b(v.x), f2b(v.y), f2b(v.z), f2b(v.w));
}

// ---------------- lin0: h0 = relu(x @ W + b)  --  MFMA bf16 GEMM ----------------
__global__ __launch_bounds__(256) void lin0_kernel(const float* __restrict__ x,
    const float* __restrict__ w, const float* __restrict__ b,
    unsigned short* __restrict__ h0)
{
    __shared__ unsigned short as_[128][40];  // A tile bf16 [m][k], rows padded 32->40
    __shared__ unsigned short wt[64][40];    // W^T chunk bf16 [n][k]
    const int tid = threadIdx.x;
    const int wv = tid >> 6, lane = tid & 63;
    const int ln15 = lane & 15, q = lane >> 4;
    const int m0 = blockIdx.x * 128;

    floatx4 acc[2][4];
#pragma unroll
    for (int i = 0; i < 2; ++i)
#pragma unroll
        for (int t = 0; t < 4; ++t) acc[i][t] = (floatx4){0.f, 0.f, 0.f, 0.f};

    const int r_ = tid >> 1, hh = tid & 1;
    int gms = m0 + r_; if (gms >= NNODES) gms = NNODES - 1;
    const float* xrow = x + (size_t)gms * NFEAT;

    for (int c = 0; c < 16; ++c) {
        const int k0 = c * 32;
        {
            float4 v0, v1, v2, v3;
            if (c < 15 || hh == 0) {
                const float4* p4 = (const float4*)(xrow + k0 + 16 * hh);
                v0 = p4[0]; v1 = p4[1]; v2 = p4[2]; v3 = p4[3];
            } else {
                v0 = *(const float4*)(xrow + 496);
                v1 = make_float4(0, 0, 0, 0); v2 = v1; v3 = v1;
            }
            ushort4* dst4 = (ushort4*)&as_[r_][16 * hh];
            dst4[0] = pk4(v0); dst4[1] = pk4(v1); dst4[2] = pk4(v2); dst4[3] = pk4(v3);
        }
#pragma unroll
        for (int ii = 0; ii < 2; ++ii) {
            int i = tid + ii * 256;
            int k = i >> 4, nb = (i & 15) * 4;
            float4 v = make_float4(0, 0, 0, 0);
            if (c < 15 || i < 320)
                v = ((const float4*)(w + (size_t)k0 * HID))[i];
            wt[nb + 0][k] = f2b(v.x); wt[nb + 1][k] = f2b(v.y);
            wt[nb + 2][k] = f2b(v.z); wt[nb + 3][k] = f2b(v.w);
        }
        __syncthreads();
        short8 af[2], bfr[4];
#pragma unroll
        for (int mt = 0; mt < 2; ++mt)
            af[mt] = *(const short8*)&as_[32 * wv + 16 * mt + ln15][8 * q];
#pragma unroll
        for (int t = 0; t < 4; ++t)
            bfr[t] = *(const short8*)&wt[16 * t + ln15][8 * q];
#pragma unroll
        for (int mt = 0; mt < 2; ++mt)
#pragma unroll
            for (int t = 0; t < 4; ++t)
                acc[mt][t] = __builtin_amdgcn_mfma_f32_16x16x32_bf16(
                    af[mt], bfr[t], acc[mt][t], 0, 0, 0);
        __syncthreads();
    }
    float bv[4];
#pragma unroll
    for (int t = 0; t < 4; ++t) bv[t] = b[16 * t + ln15];
#pragma unroll
    for (int mt = 0; mt < 2; ++mt)
#pragma unroll
        for (int r = 0; r < 4; ++r) {
            int gm = m0 + 32 * wv + 16 * mt + q * 4 + r;
            if (gm < NNODES) {
#pragma unroll
                for (int t = 0; t < 4; ++t)
                    h0[(size_t)gm * HID + 16 * t + ln15] =
                        f2b(fmaxf(acc[mt][t][r] + bv[t], 0.f));
            }
        }
}

// ---------------- CSR build, two-phase binned ----------------
// Phase A (block-aggregated two-pass): block owns a contiguous 2560-edge slice.
// Pass 1: LDS per-part histogram (wave ballot + 8 LDS atomics/wave-iter).
// Reserve: ONE global atomicAdd per part per block (10k total, not 400k).
// Pass 2: re-read slice (dst L2-hot), ballot-compact into reserved ranges.
__global__ __launch_bounds__(256) void bin_kernel(const int* __restrict__ src,
    const int* __restrict__ dst, const float* __restrict__ w,
    unsigned long long* __restrict__ staged, int* __restrict__ pcount)
{
    __shared__ int s_hist[8];
    __shared__ int s_cursor[8];
    const int tid = threadIdx.x;
    const int lane = tid & 63;
    const int e0 = blockIdx.x * EPB;
    if (tid < 8) s_hist[tid] = 0;
    __syncthreads();
#pragma unroll
    for (int it = 0; it < EPB / 256; ++it) {
        const int part = dst[e0 + it * 256 + tid] / NODES_PER_PART;
        unsigned long long m[8];
#pragma unroll
        for (int p = 0; p < 8; ++p) m[p] = __ballot(part == p);
        if (lane < 8) atomicAdd(&s_hist[lane], __popcll(m[lane]));
    }
    __syncthreads();
    if (tid < 8) s_cursor[tid] = atomicAdd(&pcount[tid], s_hist[tid]);
    __syncthreads();
    const unsigned long long below = (1ull << lane) - 1ull;
#pragma unroll
    for (int it = 0; it < EPB / 256; ++it) {
        const int e = e0 + it * 256 + tid;
        const int d = dst[e];
        const int s = src[e];
        const float wt = w[e];
        const int part = d / NODES_PER_PART;
        unsigned long long m[8];
#pragma unroll
        for (int p = 0; p < 8; ++p) m[p] = __ballot(part == p);
        int wb = 0;
        if (lane < 8) wb = atomicAdd(&s_cursor[lane], __popcll(m[lane]));
        const int mybase = __shfl(wb, part, 64);
        const int slot = mybase + __popcll(m[part] & below);
        const unsigned long long pk = (unsigned long long)(unsigned)d |
            ((unsigned long long)(unsigned)s << 17) |
            ((unsigned long long)f2b(wt) << 34);
        staged[(size_t)part * PART_CAP + slot] = pk;
    }
}

// Phase B1: degree count from staged (XCD-local atomics, nt reads).
__global__ __launch_bounds__(256) void count2_kernel(
    const unsigned long long* __restrict__ staged, const int* __restrict__ pcount,
    int* __restrict__ deg)
{
    const int part = blockIdx.x & 7;
    const int idx = (blockIdx.x >> 3) * 256 + threadIdx.x;
    if (idx < pcount[part]) {
        unsigned long long pk =
            __builtin_nontemporal_load(&staged[(size_t)part * PART_CAP + idx]);
        atomicAdd(&deg[(int)(pk & 0x1FFFFu)], 1);
    }
}

__global__ __launch_bounds__(1024) void chunk_sum_kernel(const int* __restrict__ deg,
                                                         int* __restrict__ csum)
{
    __shared__ int s[1024];
    int i = blockIdx.x * 1024 + threadIdx.x;
    s[threadIdx.x] = (i < NNODES) ? ((deg[i] + 3) & ~3) : 0;
    __syncthreads();
    for (int off = 512; off > 0; off >>= 1) {
        if (threadIdx.x < off) s[threadIdx.x] += s[threadIdx.x + off];
        __syncthreads();
    }
    if (threadIdx.x == 0) csum[blockIdx.x] = s[0];
}

__global__ void chunk_base_kernel(const int* __restrict__ csum, int* __restrict__ cbase,
                                  int* __restrict__ offs, int nchunks)
{
    int run = 0;
    for (int i = 0; i < nchunks; ++i) { cbase[i] = run; run += csum[i]; }
    offs[NNODES] = run;
}

__global__ __launch_bounds__(1024) void scan_kernel(const int* __restrict__ deg,
    const int* __restrict__ cbase, int* __restrict__ offs, int* __restrict__ cursor)
{
    __shared__ int s[1024];
    int i = blockIdx.x * 1024 + threadIdx.x;
    int v = (i < NNODES) ? ((deg[i] + 3) & ~3) : 0;
    s[threadIdx.x] = v;
    __syncthreads();
    for (int off = 1; off < 1024; off <<= 1) {
        int t = (threadIdx.x >= off) ? s[threadIdx.x - off] : 0;
        __syncthreads();
        s[threadIdx.x] += t;
        __syncthreads();
    }
    if (i < NNODES) {
        int excl = cbase[blockIdx.x] + s[threadIdx.x] - v;
        offs[i] = excl;
        cursor[i] = excl;
    }
}

// Phase B2: scatter from staged into CSR (XCD-local region, nt reads so the
// stream doesn't evict partially-written CSR lines from L2).
__global__ __launch_bounds__(256) void scatter2_kernel(
    const unsigned long long* __restrict__ staged, const int* __restrict__ pcount,
    int* __restrict__ cursor, int2* __restrict__ srcw)
{
    const int part = blockIdx.x & 7;
    const int idx = (blockIdx.x >> 3) * 256 + threadIdx.x;
    if (idx < pcount[part]) {
        unsigned long long pk =
            __builtin_nontemporal_load(&staged[(size_t)part * PART_CAP + idx]);
        const int d = (int)(pk & 0x1FFFFu);
        const int s = (int)((pk >> 17) & 0x1FFFFu);
        const float wf = b2f((unsigned short)(pk >> 34));
        int pos = atomicAdd(&cursor[d], 1);
        srcw[pos] = make_int2(s * 128, __float_as_int(wf));  // byte offset, fp32 w
    }
}

__global__ __launch_bounds__(256) void pad_kernel(const int* __restrict__ offs,
    const int* __restrict__ deg, int2* __restrict__ srcw)
{
    int n = blockIdx.x * 256 + threadIdx.x;
    if (n < NNODES) {
        int e = offs[n] + deg[n], e1 = offs[n + 1];
        for (; e < e1; ++e) srcw[e] = make_int2(0, 0);
    }
}

// ---------------- fused SpMM + blend + dense + relu layer ----------------
__global__ __launch_bounds__(256) void spmm_layer_kernel(
    const unsigned short* __restrict__ h_in, const unsigned short* __restrict__ x0,
    unsigned short* __restrict__ h_out, const int* __restrict__ offs,
    const int2* __restrict__ srcw, const float* __restrict__ Wg, float beta)
{
    __shared__ float WlT[HID][68];   // WlT[j][k] = Wg[k][j], 68-pad: conflict-free b128
    __shared__ float zs[NPB][HID];
    for (int i = threadIdx.x; i < 1024; i += 256) {
        float4 v = ((const float4*)Wg)[i];
        int k = i >> 4, j = (i & 15) * 4;
        WlT[j + 0][k] = v.x; WlT[j + 1][k] = v.y;
        WlT[j + 2][k] = v.z; WlT[j + 3][k] = v.w;
    }
    const int wv = threadIdx.x >> 6, lane = threadIdx.x & 63;
    const int half = lane >> 5, ln = lane & 31;
    const int nloc = wv + half * 4;
    const int n = blockIdx.x * NPB + nloc;
    int e = offs[n];
    const int e1 = offs[n + 1];
    const char* hb = (const char*)h_in;
    float a0 = 0.f, a1 = 0.f;
    for (; e < e1; e += 4) {         // deg padded to multiple of 4, 4 gathers in flight
        int4 p = *(const int4*)(srcw + e);
        int4 q = *(const int4*)(srcw + e + 2);
        unsigned v0 = *(const unsigned*)(hb + p.x + ln * 4);
        unsigned v1 = *(const unsigned*)(hb + p.z + ln * 4);
        unsigned v2 = *(const unsigned*)(hb + q.x + ln * 4);
        unsigned v3 = *(const unsigned*)(hb + q.z + ln * 4);
        float w0 = __int_as_float(p.y), w1 = __int_as_float(p.w);
        float w2 = __int_as_float(q.y), w3 = __int_as_float(q.w);
        a0 = fmaf(w0, __uint_as_float(v0 << 16), a0);
        a1 = fmaf(w0, __uint_as_float(v0 & 0xffff0000u), a1);
        a0 = fmaf(w1, __uint_as_float(v1 << 16), a0);
        a1 = fmaf(w1, __uint_as_float(v1 & 0xffff0000u), a1);
        a0 = fmaf(w2, __uint_as_float(v2 << 16), a0);
        a1 = fmaf(w2, __uint_as_float(v2 & 0xffff0000u), a1);
        a0 = fmaf(w3, __uint_as_float(v3 << 16), a0);
        a1 = fmaf(w3, __uint_as_float(v3 & 0xffff0000u), a1);
    }
    unsigned xv = *(const unsigned*)((const char*)x0 + (size_t)n * 128 + ln * 4);
    zs[nloc][2 * ln]     = 0.9f * a0 + 0.1f * __uint_as_float(xv << 16);
    zs[nloc][2 * ln + 1] = 0.9f * a1 + 0.1f * __uint_as_float(xv & 0xffff0000u);
    __syncthreads();
    const int j = lane;
    const int na = 2 * wv, nb = 2 * wv + 1;
    const float4* wrow = (const float4*)WlT[j];
    const float4* zap = (const float4*)zs[na];
    const float4* zbp = (const float4*)zs[nb];
    float mm0 = 0.f, mm1 = 0.f;
#pragma unroll
    for (int k4 = 0; k4 < 16; ++k4) {
        float4 wvv = wrow[k4];
        float4 za = zap[k4], zb = zbp[k4];
        mm0 = fmaf(za.x, wvv.x, mm0); mm1 = fmaf(zb.x, wvv.x, mm1);
        mm0 = fmaf(za.y, wvv.y, mm0); mm1 = fmaf(zb.y, wvv.y, mm1);
        mm0 = fmaf(za.z, wvv.z, mm0); mm1 = fmaf(zb.z, wvv.z, mm1);
        mm0 = fmaf(za.w, wvv.w, mm0); mm1 = fmaf(zb.w, wvv.w, mm1);
    }
    const float ob = 1.f - beta;
    const size_t base = (size_t)blockIdx.x * NPB;
    h_out[(base + na) * HID + j] = f2b(fmaxf(ob * zs[na][j] + beta * mm0, 0.f));
    h_out[(base + nb) * HID + j] = f2b(fmaxf(ob * zs[nb][j] + beta * mm1, 0.f));
}

// ---------------- final: log_softmax(h @ W1 + b1) ----------------
__global__ __launch_bounds__(256) void final_kernel(const unsigned short* __restrict__ h,
    const float* __restrict__ w1, const float* __restrict__ b1, float* __restrict__ out)
{
    const int m = threadIdx.x >> 6, j = threadIdx.x & 63;
    const long n = (long)blockIdx.x * 4 + m;
    const int jj = (j < NCLS) ? j : NCLS - 1;
    const ushort4* hrow = (const ushort4*)(h + n * HID);
    float acc = b1[jj];
#pragma unroll
    for (int k4 = 0; k4 < 16; ++k4) {
        ushort4 hv = hrow[k4];
        const int k = k4 * 4;
        acc = fmaf(b2f(hv.x), w1[(k + 0) * NCLS + jj], acc);
        acc = fmaf(b2f(hv.y), w1[(k + 1) * NCLS + jj], acc);
        acc = fmaf(b2f(hv.z), w1[(k + 2) * NCLS + jj], acc);
        acc = fmaf(b2f(hv.w), w1[(k + 3) * NCLS + jj], acc);
    }
    float lg = (j < NCLS) ? acc : -INFINITY;
    float mx = lg;
#pragma unroll
    for (int o = 32; o > 0; o >>= 1) mx = fmaxf(mx, __shfl_xor(mx, o, 64));
    float ex = (j < NCLS) ? expf(acc - mx) : 0.f;
    float sm = ex;
#pragma unroll
    for (int o = 32; o > 0; o >>= 1) sm += __shfl_xor(sm, o, 64);
    if (j < NCLS) out[n * NCLS + j] = acc - mx - logf(sm);
}

extern "C" void kernel_launch(void* const* d_in, const int* in_sizes, int n_in,
                              void* d_out, int out_size, void* d_ws, size_t ws_size,
                              hipStream_t stream)
{
    const float* x    = (const float*)d_in[0];
    const int*   esrc = (const int*)d_in[1];
    const int*   edst = (const int*)d_in[2];
    const float* ew   = (const float*)d_in[3];
    const float* l0w  = (const float*)d_in[4];
    const float* l0b  = (const float*)d_in[5];
    const float* cw   = (const float*)d_in[6];
    const float* l1w  = (const float*)d_in[7];
    const float* l1b  = (const float*)d_in[8];
    float* out = (float*)d_out;

    char* p = (char*)d_ws;
    unsigned short* h0 = (unsigned short*)p; p += (size_t)NNODES * HID * 2;
    unsigned short* hA = (unsigned short*)p; p += (size_t)NNODES * HID * 2;
    unsigned short* hB = (unsigned short*)p; p += (size_t)NNODES * HID * 2;
    int2*  srcw = (int2*)p;  p += ((size_t)NEDGES + 4 * NNODES) * 8;  // padded CSR
    unsigned long long* staged = (unsigned long long*)p; p += (size_t)8 * PART_CAP * 8;
    int* offs   = (int*)p;   p += (size_t)(NNODES + 1) * 4;
    int* cursor = (int*)p;   p += (size_t)NNODES * 4;
    int* deg    = (int*)p;   p += (size_t)NNODES * 4;
    int* pcount = (int*)p;   p += 64;
    int* csum   = (int*)p;   p += 512;
    int* cbase  = (int*)p;   p += 512;

    const int nchunks = (NNODES + 1023) / 1024;   // 98

    hipMemsetAsync(deg, 0, NNODES * sizeof(int) + 64, stream);  // deg + pcount
    lin0_kernel<<<(NNODES + 127) / 128, 256, 0, stream>>>(x, l0w, l0b, h0);
    bin_kernel<<<NEDGES / EPB, 256, 0, stream>>>(esrc, edst, ew, staged, pcount);
    count2_kernel<<<NBP * 8, 256, 0, stream>>>(staged, pcount, deg);
    chunk_sum_kernel<<<nchunks, 1024, 0, stream>>>(deg, csum);
    chunk_base_kernel<<<1, 1, 0, stream>>>(csum, cbase, offs, nchunks);
    scan_kernel<<<nchunks, 1024, 0, stream>>>(deg, cbase, offs, cursor);
    scatter2_kernel<<<NBP * 8, 256, 0, stream>>>(staged, pcount, cursor, srcw);
    pad_kernel<<<(NNODES + 255) / 256, 256, 0, stream>>>(offs, deg, srcw);

    const unsigned short* hin = h0;
    unsigned short* bufs[2] = { hA, hB };
    for (int l = 0; l < NLAYERS; ++l) {
        float beta = (float)log(0.5 / (double)(l + 1) + 1.0);
        unsigned short* hout = bufs[l & 1];
        spmm_layer_kernel<<<NNODES / NPB, 256, 0, stream>>>(
            hin, h0, hout, offs, srcw, cw + (size_t)l * HID * HID, beta);
        hin = hout;
    }
    final_kernel<<<NNODES / 4, 256, 0, stream>>>(hin, l1w, l1b, out);
}